// Round 1
// baseline (1107.588 us; speedup 1.0000x reference)
//
#include <hip/hip_runtime.h>
#include <math.h>

#define TPB 256

// ---------------- degree / normalization ----------------

__global__ void k_init_deg(float* __restrict__ deg, int n) {
    int i = blockIdx.x * blockDim.x + threadIdx.x;
    if (i < n) deg[i] = 1.0f;  // self-loop weight
}

__global__ void k_accum_deg(const int* __restrict__ dst, const float* __restrict__ w,
                            float* __restrict__ deg, int e) {
    int i = blockIdx.x * blockDim.x + threadIdx.x;
    if (i < e) atomicAdd(&deg[dst[i]], w[i]);
}

__global__ void k_dis(float* __restrict__ deg, int n) {
    int i = blockIdx.x * blockDim.x + threadIdx.x;
    if (i < n) {
        float d = deg[i];
        deg[i] = (d > 0.0f) ? rsqrtf(d) : 0.0f;
    }
}

// ---------------- dense GEMM  Y[n,C] = relu?(X[n,K]) @ W[K,C] ----------------

template <int K, int C, bool RELU>
__global__ __launch_bounds__(TPB) void k_gemm(const float* __restrict__ X,
                                              const float* __restrict__ W,
                                              float* __restrict__ Y, int n) {
    constexpr int ROWS = TPB / C;  // rows per tile
    __shared__ float Ws[K * C];
    __shared__ float Xs[ROWS][K];

    for (int t = threadIdx.x; t < K * C; t += TPB) Ws[t] = W[t];

    const int r = threadIdx.x / C;
    const int c = threadIdx.x % C;

    const int tiles = (n + ROWS - 1) / ROWS;
    for (int tile = blockIdx.x; tile < tiles; tile += gridDim.x) {
        const int base = tile * ROWS;
        __syncthreads();  // protect Xs (also covers first-iter Ws)
        for (int t = threadIdx.x; t < ROWS * K; t += TPB) {
            int rr = t / K, kk = t % K;
            int row = base + rr;
            float v = (row < n) ? X[(long long)row * K + kk] : 0.0f;
            if (RELU) v = fmaxf(v, 0.0f);
            Xs[rr][kk] = v;
        }
        __syncthreads();
        const int row = base + r;
        if (row < n) {
            float acc = 0.0f;
#pragma unroll
            for (int k = 0; k < K; ++k) acc = fmaf(Xs[r][k], Ws[k * C + c], acc);
            Y[(long long)row * C + c] = acc;
        }
    }
}

// ---------------- self-loop + bias init:  Y[i,c] = b[c] + dis[i]^2 * HW[i,c] ----------------

template <int C>
__global__ void k_selfinit(const float* __restrict__ HW, const float* __restrict__ dis,
                           const float* __restrict__ b, float* __restrict__ Y, int n) {
    int t = blockIdx.x * blockDim.x + threadIdx.x;
    if (t < n * C) {
        int i = t / C, c = t % C;
        float d = dis[i];
        Y[t] = b[c] + d * d * HW[t];
    }
}

// ---------------- edge scatter:  Y[dst,c] += dis[src]*w*dis[dst] * HW[src,c] ----------------

template <int C>
__global__ void k_scatter(const int* __restrict__ src, const int* __restrict__ dst,
                          const float* __restrict__ w, const float* __restrict__ dis,
                          const float* __restrict__ HW, float* __restrict__ Y, int e) {
    int t = blockIdx.x * blockDim.x + threadIdx.x;
    int total = e * C;  // max 102.4M, fits int
    if (t >= total) return;
    int edge = t / C;
    int c = t - edge * C;
    int s = src[edge];
    int d = dst[edge];
    float nrm = dis[s] * w[edge] * dis[d];
    atomicAdd(&Y[d * C + c], nrm * HW[s * C + c]);
}

// ---------------- launch ----------------

extern "C" void kernel_launch(void* const* d_in, const int* in_sizes, int n_in,
                              void* d_out, int out_size, void* d_ws, size_t ws_size,
                              hipStream_t stream) {
    const float* x  = (const float*)d_in[0];
    const int*   ei = (const int*)d_in[1];
    const float* ew = (const float*)d_in[2];
    const float* W1 = (const float*)d_in[3];
    const float* b1 = (const float*)d_in[4];
    const float* W2 = (const float*)d_in[5];
    const float* b2 = (const float*)d_in[6];
    const float* W3 = (const float*)d_in[7];
    const float* b3 = (const float*)d_in[8];
    float* out = (float*)d_out;

    const int IN_C = 128, HID_C = 64, OUT_C = 32;
    const int N = in_sizes[0] / IN_C;   // 100000
    const int E = in_sizes[2];          // 1600000

    const int* src = ei;        // edge_index[0] = row (gather source)
    const int* dst = ei + E;    // edge_index[1] = col (scatter target)

    float* dis = (float*)d_ws;                  // N floats (deg -> dis in place)
    float* A   = dis + N;                       // N*64 floats (H @ W buffer)
    float* B   = A + (size_t)N * HID_C;         // N*64 floats (layer output)

    // normalization
    k_init_deg<<<(N + TPB - 1) / TPB, TPB, 0, stream>>>(dis, N);
    k_accum_deg<<<(E + TPB - 1) / TPB, TPB, 0, stream>>>(dst, ew, dis, E);
    k_dis<<<(N + TPB - 1) / TPB, TPB, 0, stream>>>(dis, N);

    // ---- layer 1: h1 = relu( A_norm @ (x @ W1) + b1 )  (relu fused into layer2 gemm)
    k_gemm<128, 64, false><<<1024, TPB, 0, stream>>>(x, W1, A, N);
    k_selfinit<64><<<(N * 64 + TPB - 1) / TPB, TPB, 0, stream>>>(A, dis, b1, B, N);
    k_scatter<64><<<(E * 64 + TPB - 1) / TPB, TPB, 0, stream>>>(src, dst, ew, dis, A, B, E);

    // ---- layer 2: h2 = relu( A_norm @ (relu(h1) @ W2) + b2 )
    k_gemm<64, 64, true><<<1024, TPB, 0, stream>>>(B, W2, A, N);
    k_selfinit<64><<<(N * 64 + TPB - 1) / TPB, TPB, 0, stream>>>(A, dis, b2, B, N);
    k_scatter<64><<<(E * 64 + TPB - 1) / TPB, TPB, 0, stream>>>(src, dst, ew, dis, A, B, E);

    // ---- layer 3: out = A_norm @ (relu(h2) @ W3) + b3
    k_gemm<64, 32, true><<<1024, TPB, 0, stream>>>(B, W3, A, N);
    k_selfinit<32><<<(N * 32 + TPB - 1) / TPB, TPB, 0, stream>>>(A, dis, b3, out, N);
    k_scatter<32><<<(E * 32 + TPB - 1) / TPB, TPB, 0, stream>>>(src, dst, ew, dis, A, out, E);
}

// Round 2
// 943.106 us; speedup vs baseline: 1.1744x; 1.1744x over previous
//
#include <hip/hip_runtime.h>
#include <math.h>

#define TPB 256

// ---------------- normalization + degree/count ----------------

__global__ void k_init(float* __restrict__ deg, int* __restrict__ cnt, int n) {
    int i = blockIdx.x * blockDim.x + threadIdx.x;
    if (i < n) { deg[i] = 1.0f; cnt[i] = 0; }  // self-loop weight = 1
}

__global__ void k_deg_count(const int* __restrict__ dst, const float* __restrict__ w,
                            float* __restrict__ deg, int* __restrict__ cnt, int e) {
    int i = blockIdx.x * blockDim.x + threadIdx.x;
    if (i < e) {
        int d = dst[i];
        atomicAdd(&deg[d], w[i]);
        atomicAdd(&cnt[d], 1);
    }
}

__global__ void k_dis(float* __restrict__ deg, int n) {
    int i = blockIdx.x * blockDim.x + threadIdx.x;
    if (i < n) {
        float d = deg[i];
        deg[i] = (d > 0.0f) ? rsqrtf(d) : 0.0f;
    }
}

// single-workgroup exclusive scan: cnt[0..n) -> off[0..n]
__global__ __launch_bounds__(1024) void k_scan(const int* __restrict__ cnt,
                                               int* __restrict__ off, int n) {
    __shared__ int sums[1024];
    int tid = threadIdx.x;
    int chunk = (n + 1023) / 1024;
    int beg = tid * chunk;
    int end = min(beg + chunk, n);
    int s = 0;
    for (int i = beg; i < end; ++i) s += cnt[i];
    sums[tid] = s;
    __syncthreads();
    for (int d = 1; d < 1024; d <<= 1) {
        int v = (tid >= d) ? sums[tid - d] : 0;
        __syncthreads();
        sums[tid] += v;
        __syncthreads();
    }
    int run = (tid > 0) ? sums[tid - 1] : 0;  // exclusive prefix
    for (int i = beg; i < end; ++i) { off[i] = run; run += cnt[i]; }
    if (tid == 0) off[n] = sums[1023];
}

__global__ void k_zero_int(int* __restrict__ p, int n) {
    int i = blockIdx.x * blockDim.x + threadIdx.x;
    if (i < n) p[i] = 0;
}

// fill CSR: srcs[p], wnorm[p] grouped by destination
__global__ void k_fill(const int* __restrict__ src, const int* __restrict__ dst,
                       const float* __restrict__ w, const float* __restrict__ dis,
                       const int* __restrict__ off, int* __restrict__ cur,
                       int* __restrict__ srcs, float* __restrict__ wnorm, int e) {
    int i = blockIdx.x * blockDim.x + threadIdx.x;
    if (i < e) {
        int d = dst[i], s = src[i];
        int p = off[d] + atomicAdd(&cur[d], 1);
        srcs[p] = s;
        wnorm[p] = dis[s] * w[i] * dis[d];
    }
}

// ---------------- dense GEMM  Y[n,C] = relu?(X[n,K]) @ W[K,C] ----------------

template <int K, int C, bool RELU>
__global__ __launch_bounds__(TPB) void k_gemm(const float* __restrict__ X,
                                              const float* __restrict__ W,
                                              float* __restrict__ Y, int n) {
    constexpr int ROWS = TPB / C;
    __shared__ float Ws[K * C];
    __shared__ float Xs[ROWS][K];

    for (int t = threadIdx.x; t < K * C; t += TPB) Ws[t] = W[t];

    const int r = threadIdx.x / C;
    const int c = threadIdx.x % C;

    const int tiles = (n + ROWS - 1) / ROWS;
    for (int tile = blockIdx.x; tile < tiles; tile += gridDim.x) {
        const int base = tile * ROWS;
        __syncthreads();
        for (int t = threadIdx.x; t < ROWS * K; t += TPB) {
            int rr = t / K, kk = t % K;
            int row = base + rr;
            float v = (row < n) ? X[(long long)row * K + kk] : 0.0f;
            if (RELU) v = fmaxf(v, 0.0f);
            Xs[rr][kk] = v;
        }
        __syncthreads();
        const int row = base + r;
        if (row < n) {
            float acc = 0.0f;
#pragma unroll
            for (int k = 0; k < K; ++k) acc = fmaf(Xs[r][k], Ws[k * C + c], acc);
            Y[(long long)row * C + c] = acc;
        }
    }
}

// ---------------- CSR gather: one wave per node, lane = channel (C=64) ----------------

__global__ __launch_bounds__(TPB) void k_gather64(const float* __restrict__ HW,
                                                  const int* __restrict__ off,
                                                  const int* __restrict__ srcs,
                                                  const float* __restrict__ wnorm,
                                                  const float* __restrict__ dis,
                                                  const float* __restrict__ b,
                                                  float* __restrict__ Y, int n) {
    int wid = (blockIdx.x * blockDim.x + threadIdx.x) >> 6;  // node
    int lane = threadIdx.x & 63;                             // channel
    if (wid >= n) return;
    float dd = dis[wid];
    float acc = b[lane] + dd * dd * HW[wid * 64 + lane];     // self-loop + bias
    int beg = off[wid], end = off[wid + 1];
    for (int j = beg; j < end; ++j) {
        int s = srcs[j];
        acc = fmaf(wnorm[j], HW[s * 64 + lane], acc);
    }
    Y[wid * 64 + lane] = acc;
}

// C=32: lanes split into two halves, each handles alternate edges, shfl-reduce
__global__ __launch_bounds__(TPB) void k_gather32(const float* __restrict__ HW,
                                                  const int* __restrict__ off,
                                                  const int* __restrict__ srcs,
                                                  const float* __restrict__ wnorm,
                                                  const float* __restrict__ dis,
                                                  const float* __restrict__ b,
                                                  float* __restrict__ Y, int n) {
    int wid = (blockIdx.x * blockDim.x + threadIdx.x) >> 6;
    int lane = threadIdx.x & 63;
    int c = lane & 31, half = lane >> 5;
    if (wid >= n) return;
    float acc = 0.0f;
    int beg = off[wid], end = off[wid + 1];
    for (int j = beg + half; j < end; j += 2)
        acc = fmaf(wnorm[j], HW[srcs[j] * 32 + c], acc);
    acc += __shfl_xor(acc, 32);
    if (half == 0) {
        float dd = dis[wid];
        Y[wid * 32 + c] = acc + b[c] + dd * dd * HW[wid * 32 + c];
    }
}

// ---------------- launch ----------------

extern "C" void kernel_launch(void* const* d_in, const int* in_sizes, int n_in,
                              void* d_out, int out_size, void* d_ws, size_t ws_size,
                              hipStream_t stream) {
    const float* x  = (const float*)d_in[0];
    const int*   ei = (const int*)d_in[1];
    const float* ew = (const float*)d_in[2];
    const float* W1 = (const float*)d_in[3];
    const float* b1 = (const float*)d_in[4];
    const float* W2 = (const float*)d_in[5];
    const float* b2 = (const float*)d_in[6];
    const float* W3 = (const float*)d_in[7];
    const float* b3 = (const float*)d_in[8];
    float* out = (float*)d_out;

    const int IN_C = 128, HID_C = 64;
    const int N = in_sizes[0] / IN_C;   // 100000
    const int E = in_sizes[2];          // 1600000

    const int* src = ei;       // edge_index[0] = row (gather source)
    const int* dst = ei + E;   // edge_index[1] = col (destination)

    // workspace layout (all 4-byte elems): ~65 MB total
    char* w = (char*)d_ws;
    float* dis   = (float*)w;                 w += sizeof(float) * N;
    int*   off   = (int*)w;                   w += sizeof(int) * (N + 1);
    int*   cur   = (int*)w;                   w += sizeof(int) * N;
    int*   srcs  = (int*)w;                   w += sizeof(int) * E;
    float* wnorm = (float*)w;                 w += sizeof(float) * E;
    float* A     = (float*)w;                 w += sizeof(float) * (size_t)N * HID_C;
    float* B     = (float*)w;                 /* N*HID_C floats */

    const int gN = (N + TPB - 1) / TPB;
    const int gE = (E + TPB - 1) / TPB;

    // ---- build normalization + CSR ----
    k_init<<<gN, TPB, 0, stream>>>(dis, cur, N);
    k_deg_count<<<gE, TPB, 0, stream>>>(dst, ew, dis, cur, E);
    k_dis<<<gN, TPB, 0, stream>>>(dis, N);
    k_scan<<<1, 1024, 0, stream>>>(cur, off, N);
    k_zero_int<<<gN, TPB, 0, stream>>>(cur, N);
    k_fill<<<gE, TPB, 0, stream>>>(src, dst, ew, dis, off, cur, srcs, wnorm, E);

    const int gW64 = ((size_t)N * 64 + TPB - 1) / TPB;  // one wave per node

    // ---- layer 1 ----
    k_gemm<128, 64, false><<<1024, TPB, 0, stream>>>(x, W1, A, N);
    k_gather64<<<gW64, TPB, 0, stream>>>(A, off, srcs, wnorm, dis, b1, B, N);

    // ---- layer 2 ----
    k_gemm<64, 64, true><<<1024, TPB, 0, stream>>>(B, W2, A, N);
    k_gather64<<<gW64, TPB, 0, stream>>>(A, off, srcs, wnorm, dis, b2, B, N);

    // ---- layer 3 ----
    k_gemm<64, 32, true><<<1024, TPB, 0, stream>>>(B, W3, A, N);
    k_gather32<<<gW64, TPB, 0, stream>>>(A, off, srcs, wnorm, dis, b3, out, N);
}